// Round 7
// baseline (244.699 us; speedup 1.0000x reference)
//
#include <hip/hip_runtime.h>
#include <hip/hip_bf16.h>

#define DEV static __device__ __forceinline__

typedef __attribute__((ext_vector_type(8))) short short8;
typedef __attribute__((ext_vector_type(4))) float f32x4;
typedef __attribute__((ext_vector_type(4))) float float4v;
typedef __attribute__((ext_vector_type(4))) unsigned int uint4v;
typedef __attribute__((ext_vector_type(2))) unsigned int uint2v;

// ---- helpers -------------------------------------------------------------

DEV unsigned short f2bf(float f) {
  union { float f; unsigned u; } x{f};
  return (unsigned short)((x.u + 0x7fffu + ((x.u >> 16) & 1u)) >> 16);  // RNE
}

DEV unsigned pack_bf(float lo, float hi) {
  return (unsigned)f2bf(lo) | ((unsigned)f2bf(hi) << 16);
}

DEV float fast_exp2(float x) { return __builtin_amdgcn_exp2f(x); }
DEV float fast_log2(float x) { return __builtin_amdgcn_logf(x); }

DEV f32x4 mfma16(short8 a, short8 b, f32x4 c) {
  return __builtin_amdgcn_mfma_f32_16x16x32_bf16(a, b, c, 0, 0, 0);
}

DEV void gload16(const void* g, void* l) {
  __builtin_amdgcn_global_load_lds(
      (const __attribute__((address_space(1))) unsigned*)g,
      (__attribute__((address_space(3))) unsigned*)l, 16, 0, 0);
}

// ---- kernel 1: all 3 weight transposes in ONE launch ---------------------
// dst[n][k] = bf16(src[k][n]); 1024 blocks: [0,256) Wq, [256,768) Wkv,
// [768,1024) Wo.
__global__ __launch_bounds__(256) void transpose_cvt3(
    const float* __restrict__ Wq, const float* __restrict__ Wkv,
    const float* __restrict__ Wo, unsigned short* __restrict__ WqT,
    unsigned short* __restrict__ WkvT, unsigned short* __restrict__ WoT) {
  __shared__ float tile[32][33];
  const int bid = blockIdx.x;
  const float* src;
  unsigned short* dst;
  int Nd, local;
  if (bid < 256) { src = Wq; dst = WqT; Nd = 512; local = bid; }
  else if (bid < 768) { src = Wkv; dst = WkvT; Nd = 1024; local = bid - 256; }
  else { src = Wo; dst = WoT; Nd = 512; local = bid - 768; }
  const int k0 = (local & 15) * 32;
  const int n0 = (local >> 4) * 32;
  const int tx = threadIdx.x & 31, ty = threadIdx.x >> 5;
#pragma unroll
  for (int i = 0; i < 4; ++i)
    tile[ty + i * 8][tx] = src[(size_t)(k0 + ty + i * 8) * Nd + n0 + tx];
  __syncthreads();
#pragma unroll
  for (int i = 0; i < 4; ++i)
    dst[(size_t)(n0 + ty + i * 8) * 512 + k0 + tx] = f2bf(tile[tx][ty + i * 8]);
}

// ---- kernels 2/3/5: 128x128 MFMA GEMM, K=512, BK=64 ----------------------
// MODE 0: A=fp32 query, epilogue -> Qb bf16 [B,H,2048,64], scaled 0.125
// MODE 1: A=fp32 memory, epilogue -> Kb bf16 [B,H,512,64] + VT bf16 [B,H,64,512]
// MODE 2: A=bf16 y,     epilogue -> out fp32 [16384,512]
// 1-D grid, XCD-aware: each XCD owns whole A row-panels; a panel's col-blocks
// are dispatch-adjacent on the SAME XCD.
template <int MODE>
__global__ __launch_bounds__(256, 2) void gemm_kernel(
    const void* __restrict__ Aptr, const unsigned short* __restrict__ WT,
    void* __restrict__ out0, void* __restrict__ out1) {
  __shared__ char smemA[16384];
  __shared__ char smemB[16384];
  const int tid = threadIdx.x;
  const int w = tid >> 6, l = tid & 63, c = l & 15, g = l >> 4;
  const int wm = w >> 1, wn = w & 1;

  const int bid = blockIdx.x;
  const int xcd = bid & 7, idx = bid >> 3;
  constexpr int NCB = (MODE == 1) ? 3 : 2;   // log2(col-blocks)
  constexpr int NRX = (MODE == 1) ? 4 : 16;  // row-panels per XCD
  const int row0 = (xcd * NRX + (idx >> NCB)) * 128;
  const int col0 = (idx & ((1 << NCB) - 1)) * 128;

  f32x4 acc[4][4];
#pragma unroll
  for (int m = 0; m < 4; ++m)
#pragma unroll
    for (int n = 0; n < 4; ++n) acc[m][n] = f32x4{0.f, 0.f, 0.f, 0.f};

  for (int kt = 0; kt < 8; ++kt) {
    if (MODE != 2) {
      const int arow = tid >> 1, ahalf = tid & 1;
      const float* asrc =
          (const float*)Aptr + (size_t)(row0 + arow) * 512 + kt * 64 + ahalf * 32;
      float4v av[8];
#pragma unroll
      for (int i = 0; i < 8; ++i) av[i] = *(const float4v*)(asrc + i * 4);
#pragma unroll
      for (int qq = 0; qq < 4; ++qq) {
        uint4v pk;
        pk.x = pack_bf(av[2 * qq][0], av[2 * qq][1]);
        pk.y = pack_bf(av[2 * qq][2], av[2 * qq][3]);
        pk.z = pack_bf(av[2 * qq + 1][0], av[2 * qq + 1][1]);
        pk.w = pack_bf(av[2 * qq + 1][2], av[2 * qq + 1][3]);
        int off = (arow * 128 + ahalf * 64 + qq * 16) ^ ((arow & 7) << 4);
        *(uint4v*)(smemA + off) = pk;
      }
    } else {
#pragma unroll
      for (int cc = 0; cc < 4; ++cc) {
        int o = cc * 4096 + tid * 16;
        int r_ = o >> 7;
        gload16((const char*)Aptr + (size_t)(row0 + r_) * 1024 + kt * 128 +
                    ((o ^ ((r_ & 7) << 4)) & 127),
                smemA + o);
      }
    }
#pragma unroll
    for (int cc = 0; cc < 4; ++cc) {
      int o = cc * 4096 + tid * 16;
      int r_ = o >> 7;
      gload16((const char*)WT + (size_t)(col0 + r_) * 1024 + kt * 128 +
                  ((o ^ ((r_ & 7) << 4)) & 127),
              smemB + o);
    }
    __syncthreads();
#pragma unroll
    for (int s = 0; s < 2; ++s) {
      short8 af[4], bfr[4];
#pragma unroll
      for (int m = 0; m < 4; ++m) {
        int row = wm * 64 + m * 16 + c;
        af[m] = *(const short8*)(smemA +
                                 ((row * 128 + g * 16 + s * 64) ^ ((row & 7) << 4)));
      }
#pragma unroll
      for (int n = 0; n < 4; ++n) {
        int row = wn * 64 + n * 16 + c;
        bfr[n] = *(const short8*)(smemB +
                                  ((row * 128 + g * 16 + s * 64) ^ ((row & 7) << 4)));
      }
#pragma unroll
      for (int m = 0; m < 4; ++m)
#pragma unroll
        for (int n = 0; n < 4; ++n) acc[m][n] = mfma16(af[m], bfr[n], acc[m][n]);
    }
    __syncthreads();
  }

#pragma unroll
  for (int m = 0; m < 4; ++m)
#pragma unroll
    for (int n = 0; n < 4; ++n)
#pragma unroll
      for (int r = 0; r < 4; ++r) {
        float v = acc[m][n][r];
        int grow = row0 + wm * 64 + m * 16 + g * 4 + r;
        int gcol = col0 + wn * 64 + n * 16 + c;
        if (MODE == 0) {
          int bb = grow >> 11, q = grow & 2047, hh = gcol >> 6, d = gcol & 63;
          ((unsigned short*)out0)[(((size_t)bb * 8 + hh) * 2048 + q) * 64 + d] =
              f2bf(v * 0.125f);
        } else if (MODE == 1) {
          int bb = grow >> 9, t2 = grow & 511;
          if (gcol < 512) {
            int hh = gcol >> 6, d = gcol & 63;
            ((unsigned short*)out0)[(((size_t)bb * 8 + hh) * 512 + t2) * 64 + d] =
                f2bf(v);
          } else {
            int hh = (gcol - 512) >> 6, d = gcol & 63;
            ((unsigned short*)out1)[(((size_t)bb * 8 + hh) * 64 + d) * 512 + t2] =
                f2bf(v);
          }
        } else {
          __builtin_nontemporal_store(
              v, (float*)out0 + (size_t)grow * 512 + gcol);
        }
      }
}

// ---- kernel 4: fused attention, flash-tiled ------------------------------
// grid = 2048 (XCD-chunked; h fastest within chunk); block = 256 (4 waves x
// 16 q-rows). KV processed in 4 tiles of 128, double-buffered LDS.
// softmax(log_softmax(S)+logp) == softmax(S+logp); no max needed.
// Score/prob stores are PLAIN (not nt): the 16B/lane pieces at 2KB row
// stride need L2 to assemble full lines; nt evicts 64B-dirty lines early ->
// HBM read-modify-write at half write BW (the A/B this round tests).
// PV also operand-swapped: lane holds y[q=c][d=nt*16+g*4+r] -> packed 8B
// y-stores and rs applies directly (no shfl).
__global__ __launch_bounds__(256, 2) void attn_kernel(
    const unsigned short* __restrict__ Qb, const unsigned short* __restrict__ Kb,
    const unsigned short* __restrict__ VTb, const float* __restrict__ prior,
    float* __restrict__ score, float* __restrict__ prob,
    unsigned short* __restrict__ yb) {
  extern __shared__ char smem[];
  char* kl[2] = {smem, smem + 16384};
  char* vl[2] = {smem + 32768, smem + 49152};
  const int tid = threadIdx.x;
  const int w = tid >> 6, l = tid & 63;
  const int c = l & 15, g = l >> 4;
  char* pw = smem + 65536 + w * 4096;

  // XCD-chunked bijective swizzle (2048 % 8 == 0): each XCD gets one b.
  const int xid = (blockIdx.x & 7) * 256 + (blockIdx.x >> 3);
  const int h = xid & 7, qt = (xid >> 3) & 31, b = xid >> 8;
  const int bh = b * 8 + h;
  const int q0 = qt * 64;

  const char* kbase = (const char*)(Kb + (size_t)bh * 512 * 64);
  const char* vbase = (const char*)(VTb + (size_t)bh * 64 * 512);

  auto stageK = [&](int t, char* dst) {
    const char* src = kbase + (size_t)t * 16384;
#pragma unroll
    for (int i = 0; i < 4; ++i) {
      int o = i * 4096 + tid * 16;
      int row = o >> 7;
      gload16(src + row * 128 + ((o & 127) ^ ((row & 7) << 4)), dst + o);
    }
  };
  auto stageV = [&](int t, char* dst) {
#pragma unroll
    for (int i = 0; i < 4; ++i) {
      int o = i * 4096 + tid * 16;
      int row = o >> 8;
      gload16(vbase + row * 1024 + t * 256 + ((o & 255) ^ ((row & 7) << 4)),
              dst + o);
    }
  };

  stageK(0, kl[0]);
  stageV(0, vl[0]);

  // Q fragments from global (row stride 128B), pre-scaled by 0.125
  const char* qbase = (const char*)(Qb + ((size_t)bh * 2048 + q0 + w * 16) * 64);
  short8 qf0 = *(const short8*)(qbase + c * 128 + g * 16);
  short8 qf1 = *(const short8*)(qbase + c * 128 + g * 16 + 64);

  const int q = q0 + w * 16 + c;
  float* sb = score + ((size_t)bh * 2048 + q) * 512 + g * 4;
  float* pb = prob + ((size_t)bh * 2048 + q) * 512 + g * 4;
  const float* prb = prior + ((size_t)b * 2048 + q) * 512 + g * 4;

  f32x4 acc[32];
#pragma unroll
  for (int n = 0; n < 32; ++n) acc[n] = f32x4{0.f, 0.f, 0.f, 0.f};
  f32x4 yacc[4];
#pragma unroll
  for (int n = 0; n < 4; ++n) yacc[n] = f32x4{0.f, 0.f, 0.f, 0.f};
  float rsum = 0.f;

  __syncthreads();  // tile 0 staged

#pragma unroll
  for (int t = 0; t < 4; ++t) {
    const int cur = t & 1;
    if (t < 3) {  // prefetch next K/V tile while computing this one
      stageK(t + 1, kl[cur ^ 1]);
      stageV(t + 1, vl[cur ^ 1]);
    }
    // prefetch this tile's prior into regs; latency hides under QK^T MFMA
    float4v pr[8];
#pragma unroll
    for (int n = 0; n < 8; ++n)
      pr[n] = *(const float4v*)(prb + t * 128 + n * 16);

    // S^T = K Q^T : acc[t*8+n] = S[q][k = t*128 + n*16 + g*4 .. +3]
#pragma unroll
    for (int n = 0; n < 8; ++n) {
      const int a = t * 8 + n;
      const int krow = n * 16 + c;
      const int base = krow * 128 + g * 16;
      short8 kf0 = *(const short8*)(kl[cur] + (base ^ ((krow & 7) << 4)));
      short8 kf1 = *(const short8*)(kl[cur] + ((base + 64) ^ ((krow & 7) << 4)));
      acc[a] = mfma16(kf0, qf0, acc[a]);
      acc[a] = mfma16(kf1, qf1, acc[a]);
    }
    // score store + e = exp2(S*log2e + log2(prior+eps)) + P-tile (bf16)
#pragma unroll
    for (int n = 0; n < 8; ++n) {
      const int a = t * 8 + n;
      *(float4v*)(sb + t * 128 + n * 16) = (float4v)acc[a];
      f32x4 e;
#pragma unroll
      for (int r = 0; r < 4; ++r)
        e[r] = fast_exp2(acc[a][r] * 1.44269504f + fast_log2(pr[n][r] + 1e-8f));
      rsum += (e[0] + e[1]) + (e[2] + e[3]);
      acc[a] = e;
      uint2v u;
      u.x = pack_bf(e[0], e[1]);
      u.y = pack_bf(e[2], e[3]);
      *(uint2v*)(pw + ((c * 256 + n * 32 + g * 8) ^ ((c & 7) << 4))) = u;
    }
    // y += V^T x P (SWAPPED): lane gets y[q=c][d = nt*16 + g*4 + r]
#pragma unroll
    for (int s = 0; s < 4; ++s) {
      short8 pf =
          *(const short8*)(pw + ((c * 256 + s * 64 + g * 16) ^ ((c & 7) << 4)));
#pragma unroll
      for (int nt = 0; nt < 4; ++nt) {
        const int vrow = nt * 16 + c;
        short8 vf = *(const short8*)(
            vl[cur] + ((vrow * 256 + s * 64 + g * 16) ^ ((vrow & 7) << 4)));
        yacc[nt] = mfma16(vf, pf, yacc[nt]);
      }
    }
    __syncthreads();  // tile t consumed by all waves; tile t+1 staged
  }

  // row sum for q-row c: spread across lanes differing in bits 4,5
  rsum += __shfl_xor(rsum, 16);
  rsum += __shfl_xor(rsum, 32);
  const float rs = 1.f / rsum;

  // prob = e * rs (dwordx4) — lane's own q-row is c: rs correct.
#pragma unroll
  for (int n = 0; n < 32; ++n) {
    float4v p;
#pragma unroll
    for (int r = 0; r < 4; ++r) p[r] = acc[n][r] * rs;
    *(float4v*)(pb + n * 16) = p;
  }

  // y store: lane holds y[q=c][d=nt*16+g*4+r] -> 4 packed 8B stores, own rs.
  unsigned short* yb_ =
      yb + ((size_t)b * 2048 + q0 + w * 16 + c) * 512 + h * 64;
#pragma unroll
  for (int nt = 0; nt < 4; ++nt) {
    uint2v u;
    u.x = pack_bf(yacc[nt][0] * rs, yacc[nt][1] * rs);
    u.y = pack_bf(yacc[nt][2] * rs, yacc[nt][3] * rs);
    *(uint2v*)(yb_ + nt * 16 + g * 4) = u;
  }
}

// ---- launcher ------------------------------------------------------------

extern "C" void kernel_launch(void* const* d_in, const int* in_sizes, int n_in,
                              void* d_out, int out_size, void* d_ws, size_t ws_size,
                              hipStream_t stream) {
  (void)in_sizes; (void)n_in; (void)out_size;
  const float* query = (const float*)d_in[0];
  const float* memory = (const float*)d_in[2];
  const float* prior = (const float*)d_in[4];
  const float* Wq = (const float*)d_in[5];
  const float* Wkv = (const float*)d_in[6];
  const float* Wo = (const float*)d_in[7];

  float* out = (float*)d_out;
  float* prob = out + (size_t)8 * 2048 * 512;          // 8388608
  float* score = prob + (size_t)64 * 2048 * 512;       // +67108864

  char* ws = (char*)d_ws;
  size_t off = 0;
  unsigned short* WqT = (unsigned short*)(ws + off);  off += (size_t)512 * 512 * 2;
  unsigned short* WkvT = (unsigned short*)(ws + off); off += (size_t)1024 * 512 * 2;
  unsigned short* WoT = (unsigned short*)(ws + off);  off += (size_t)512 * 512 * 2;
  unsigned short* Qb = (unsigned short*)(ws + off);   off += (size_t)64 * 2048 * 64 * 2;
  unsigned short* Kb = (unsigned short*)(ws + off);   off += (size_t)64 * 512 * 64 * 2;
  unsigned short* VT = (unsigned short*)(ws + off);   off += (size_t)64 * 64 * 512 * 2;
  unsigned short* yb = (unsigned short*)(ws + off);   off += (size_t)8 * 2048 * 512 * 2;
  if (ws_size < off) return;  // fail loudly (output stays poisoned)

  (void)hipFuncSetAttribute((const void*)attn_kernel,
                            hipFuncAttributeMaxDynamicSharedMemorySize, 81920);

  transpose_cvt3<<<1024, 256, 0, stream>>>(Wq, Wkv, Wo, WqT, WkvT, WoT);
  gemm_kernel<0><<<512, 256, 0, stream>>>(query, WqT, Qb, nullptr);
  gemm_kernel<1><<<256, 256, 0, stream>>>(memory, WkvT, Kb, VT);
  attn_kernel<<<2048, 256, 81920, stream>>>(Qb, Kb, VT, prior, score, prob, yb);
  gemm_kernel<2><<<512, 256, 0, stream>>>(yb, WoT, out, nullptr);
}

// Round 8
// 227.400 us; speedup vs baseline: 1.0761x; 1.0761x over previous
//
#include <hip/hip_runtime.h>
#include <hip/hip_bf16.h>

#define DEV static __device__ __forceinline__

typedef __attribute__((ext_vector_type(8))) short short8;
typedef __attribute__((ext_vector_type(4))) float f32x4;
typedef __attribute__((ext_vector_type(4))) float float4v;
typedef __attribute__((ext_vector_type(4))) unsigned int uint4v;
typedef __attribute__((ext_vector_type(2))) unsigned int uint2v;

// ---- helpers -------------------------------------------------------------

DEV unsigned short f2bf(float f) {
  union { float f; unsigned u; } x{f};
  return (unsigned short)((x.u + 0x7fffu + ((x.u >> 16) & 1u)) >> 16);  // RNE
}

DEV unsigned pack_bf(float lo, float hi) {
  return (unsigned)f2bf(lo) | ((unsigned)f2bf(hi) << 16);
}

DEV float fast_exp2(float x) { return __builtin_amdgcn_exp2f(x); }
DEV float fast_log2(float x) { return __builtin_amdgcn_logf(x); }

DEV f32x4 mfma16(short8 a, short8 b, f32x4 c) {
  return __builtin_amdgcn_mfma_f32_16x16x32_bf16(a, b, c, 0, 0, 0);
}

DEV void gload16(const void* g, void* l) {
  __builtin_amdgcn_global_load_lds(
      (const __attribute__((address_space(1))) unsigned*)g,
      (__attribute__((address_space(3))) unsigned*)l, 16, 0, 0);
}

// ---- kernel 1: all 3 weight transposes in ONE launch ---------------------
__global__ __launch_bounds__(256) void transpose_cvt3(
    const float* __restrict__ Wq, const float* __restrict__ Wkv,
    const float* __restrict__ Wo, unsigned short* __restrict__ WqT,
    unsigned short* __restrict__ WkvT, unsigned short* __restrict__ WoT) {
  __shared__ float tile[32][33];
  const int bid = blockIdx.x;
  const float* src;
  unsigned short* dst;
  int Nd, local;
  if (bid < 256) { src = Wq; dst = WqT; Nd = 512; local = bid; }
  else if (bid < 768) { src = Wkv; dst = WkvT; Nd = 1024; local = bid - 256; }
  else { src = Wo; dst = WoT; Nd = 512; local = bid - 768; }
  const int k0 = (local & 15) * 32;
  const int n0 = (local >> 4) * 32;
  const int tx = threadIdx.x & 31, ty = threadIdx.x >> 5;
#pragma unroll
  for (int i = 0; i < 4; ++i)
    tile[ty + i * 8][tx] = src[(size_t)(k0 + ty + i * 8) * Nd + n0 + tx];
  __syncthreads();
#pragma unroll
  for (int i = 0; i < 4; ++i)
    dst[(size_t)(n0 + ty + i * 8) * 512 + k0 + tx] = f2bf(tile[tx][ty + i * 8]);
}

// ---- kernels 2/3/5: 128x128 MFMA GEMM, K=512, BK=64 ----------------------
// MODE 0: A=fp32 query, epilogue -> Qb bf16 [B,H,2048,64], scaled 0.125
// MODE 1: A=fp32 memory, epilogue -> Kb bf16 [B,H,512,64] + VT bf16 [B,H,64,512]
// MODE 2: A=bf16 y,     epilogue -> out fp32 [16384,512]
// 1-D grid, XCD-aware: each XCD owns whole A row-panels; a panel's col-blocks
// are dispatch-adjacent on the SAME XCD.
template <int MODE>
__global__ __launch_bounds__(256, 2) void gemm_kernel(
    const void* __restrict__ Aptr, const unsigned short* __restrict__ WT,
    void* __restrict__ out0, void* __restrict__ out1) {
  __shared__ char smemA[16384];
  __shared__ char smemB[16384];
  const int tid = threadIdx.x;
  const int w = tid >> 6, l = tid & 63, c = l & 15, g = l >> 4;
  const int wm = w >> 1, wn = w & 1;

  const int bid = blockIdx.x;
  const int xcd = bid & 7, idx = bid >> 3;
  constexpr int NCB = (MODE == 1) ? 3 : 2;   // log2(col-blocks)
  constexpr int NRX = (MODE == 1) ? 4 : 16;  // row-panels per XCD
  const int row0 = (xcd * NRX + (idx >> NCB)) * 128;
  const int col0 = (idx & ((1 << NCB) - 1)) * 128;

  f32x4 acc[4][4];
#pragma unroll
  for (int m = 0; m < 4; ++m)
#pragma unroll
    for (int n = 0; n < 4; ++n) acc[m][n] = f32x4{0.f, 0.f, 0.f, 0.f};

  for (int kt = 0; kt < 8; ++kt) {
    if (MODE != 2) {
      const int arow = tid >> 1, ahalf = tid & 1;
      const float* asrc =
          (const float*)Aptr + (size_t)(row0 + arow) * 512 + kt * 64 + ahalf * 32;
      float4v av[8];
#pragma unroll
      for (int i = 0; i < 8; ++i) av[i] = *(const float4v*)(asrc + i * 4);
#pragma unroll
      for (int qq = 0; qq < 4; ++qq) {
        uint4v pk;
        pk.x = pack_bf(av[2 * qq][0], av[2 * qq][1]);
        pk.y = pack_bf(av[2 * qq][2], av[2 * qq][3]);
        pk.z = pack_bf(av[2 * qq + 1][0], av[2 * qq + 1][1]);
        pk.w = pack_bf(av[2 * qq + 1][2], av[2 * qq + 1][3]);
        int off = (arow * 128 + ahalf * 64 + qq * 16) ^ ((arow & 7) << 4);
        *(uint4v*)(smemA + off) = pk;
      }
    } else {
#pragma unroll
      for (int cc = 0; cc < 4; ++cc) {
        int o = cc * 4096 + tid * 16;
        int r_ = o >> 7;
        gload16((const char*)Aptr + (size_t)(row0 + r_) * 1024 + kt * 128 +
                    ((o ^ ((r_ & 7) << 4)) & 127),
                smemA + o);
      }
    }
#pragma unroll
    for (int cc = 0; cc < 4; ++cc) {
      int o = cc * 4096 + tid * 16;
      int r_ = o >> 7;
      gload16((const char*)WT + (size_t)(col0 + r_) * 1024 + kt * 128 +
                  ((o ^ ((r_ & 7) << 4)) & 127),
              smemB + o);
    }
    __syncthreads();
#pragma unroll
    for (int s = 0; s < 2; ++s) {
      short8 af[4], bfr[4];
#pragma unroll
      for (int m = 0; m < 4; ++m) {
        int row = wm * 64 + m * 16 + c;
        af[m] = *(const short8*)(smemA +
                                 ((row * 128 + g * 16 + s * 64) ^ ((row & 7) << 4)));
      }
#pragma unroll
      for (int n = 0; n < 4; ++n) {
        int row = wn * 64 + n * 16 + c;
        bfr[n] = *(const short8*)(smemB +
                                  ((row * 128 + g * 16 + s * 64) ^ ((row & 7) << 4)));
      }
      __builtin_amdgcn_s_setprio(1);
#pragma unroll
      for (int m = 0; m < 4; ++m)
#pragma unroll
        for (int n = 0; n < 4; ++n) acc[m][n] = mfma16(af[m], bfr[n], acc[m][n]);
      __builtin_amdgcn_s_setprio(0);
    }
    __syncthreads();
  }

#pragma unroll
  for (int m = 0; m < 4; ++m)
#pragma unroll
    for (int n = 0; n < 4; ++n)
#pragma unroll
      for (int r = 0; r < 4; ++r) {
        float v = acc[m][n][r];
        int grow = row0 + wm * 64 + m * 16 + g * 4 + r;
        int gcol = col0 + wn * 64 + n * 16 + c;
        if (MODE == 0) {
          int bb = grow >> 11, q = grow & 2047, hh = gcol >> 6, d = gcol & 63;
          ((unsigned short*)out0)[(((size_t)bb * 8 + hh) * 2048 + q) * 64 + d] =
              f2bf(v * 0.125f);
        } else if (MODE == 1) {
          int bb = grow >> 9, t2 = grow & 511;
          if (gcol < 512) {
            int hh = gcol >> 6, d = gcol & 63;
            ((unsigned short*)out0)[(((size_t)bb * 8 + hh) * 512 + t2) * 64 + d] =
                f2bf(v);
          } else {
            int hh = (gcol - 512) >> 6, d = gcol & 63;
            ((unsigned short*)out1)[(((size_t)bb * 8 + hh) * 64 + d) * 512 + t2] =
                f2bf(v);
          }
        } else {
          __builtin_nontemporal_store(
              v, (float*)out0 + (size_t)grow * 512 + gcol);
        }
      }
}

// ---- kernel 4: fused attention, flash-tiled ------------------------------
// grid = 2048 (XCD-chunked; h fastest within chunk); block = 256 (4 waves x
// 16 q-rows). KV processed in 4 tiles of 128, double-buffered LDS.
// softmax(log_softmax(S)+logp) == softmax(S+logp); no max needed.
// Score/prob stores NON-TEMPORAL (R7 A/B: plain stores thrash L2, +15us —
// NT keeps the 536MB write stream out of L2 so prior rows survive for the
// 8 h-neighbor blocks on the same XCD).
// PV operand-swapped: lane holds y[q=c][d=nt*16+g*4+r] -> packed 8B y-stores,
// own-lane rs. s_setprio(1) wraps MFMA clusters (T5: co-resident block is
// phase-diverse -> scheduler favors the MFMA wave).
__global__ __launch_bounds__(256, 2) void attn_kernel(
    const unsigned short* __restrict__ Qb, const unsigned short* __restrict__ Kb,
    const unsigned short* __restrict__ VTb, const float* __restrict__ prior,
    float* __restrict__ score, float* __restrict__ prob,
    unsigned short* __restrict__ yb) {
  extern __shared__ char smem[];
  char* kl[2] = {smem, smem + 16384};
  char* vl[2] = {smem + 32768, smem + 49152};
  const int tid = threadIdx.x;
  const int w = tid >> 6, l = tid & 63;
  const int c = l & 15, g = l >> 4;
  char* pw = smem + 65536 + w * 4096;

  // XCD-chunked bijective swizzle (2048 % 8 == 0): each XCD gets one b.
  const int xid = (blockIdx.x & 7) * 256 + (blockIdx.x >> 3);
  const int h = xid & 7, qt = (xid >> 3) & 31, b = xid >> 8;
  const int bh = b * 8 + h;
  const int q0 = qt * 64;

  const char* kbase = (const char*)(Kb + (size_t)bh * 512 * 64);
  const char* vbase = (const char*)(VTb + (size_t)bh * 64 * 512);

  auto stageK = [&](int t, char* dst) {
    const char* src = kbase + (size_t)t * 16384;
#pragma unroll
    for (int i = 0; i < 4; ++i) {
      int o = i * 4096 + tid * 16;
      int row = o >> 7;
      gload16(src + row * 128 + ((o & 127) ^ ((row & 7) << 4)), dst + o);
    }
  };
  auto stageV = [&](int t, char* dst) {
#pragma unroll
    for (int i = 0; i < 4; ++i) {
      int o = i * 4096 + tid * 16;
      int row = o >> 8;
      gload16(vbase + row * 1024 + t * 256 + ((o & 255) ^ ((row & 7) << 4)),
              dst + o);
    }
  };

  stageK(0, kl[0]);
  stageV(0, vl[0]);

  // Q fragments from global (row stride 128B), pre-scaled by 0.125
  const char* qbase = (const char*)(Qb + ((size_t)bh * 2048 + q0 + w * 16) * 64);
  short8 qf0 = *(const short8*)(qbase + c * 128 + g * 16);
  short8 qf1 = *(const short8*)(qbase + c * 128 + g * 16 + 64);

  const int q = q0 + w * 16 + c;
  float* sb = score + ((size_t)bh * 2048 + q) * 512 + g * 4;
  float* pb = prob + ((size_t)bh * 2048 + q) * 512 + g * 4;
  const float* prb = prior + ((size_t)b * 2048 + q) * 512 + g * 4;

  f32x4 acc[32];
#pragma unroll
  for (int n = 0; n < 32; ++n) acc[n] = f32x4{0.f, 0.f, 0.f, 0.f};
  f32x4 yacc[4];
#pragma unroll
  for (int n = 0; n < 4; ++n) yacc[n] = f32x4{0.f, 0.f, 0.f, 0.f};
  float rsum = 0.f;

  __syncthreads();  // tile 0 staged

#pragma unroll
  for (int t = 0; t < 4; ++t) {
    const int cur = t & 1;
    if (t < 3) {  // prefetch next K/V tile while computing this one
      stageK(t + 1, kl[cur ^ 1]);
      stageV(t + 1, vl[cur ^ 1]);
    }
    // prefetch this tile's prior into regs; latency hides under QK^T MFMA
    float4v pr[8];
#pragma unroll
    for (int n = 0; n < 8; ++n)
      pr[n] = *(const float4v*)(prb + t * 128 + n * 16);

    // S^T = K Q^T : acc[t*8+n] = S[q][k = t*128 + n*16 + g*4 .. +3]
#pragma unroll
    for (int n = 0; n < 8; ++n) {
      const int a = t * 8 + n;
      const int krow = n * 16 + c;
      const int base = krow * 128 + g * 16;
      short8 kf0 = *(const short8*)(kl[cur] + (base ^ ((krow & 7) << 4)));
      short8 kf1 = *(const short8*)(kl[cur] + ((base + 64) ^ ((krow & 7) << 4)));
      __builtin_amdgcn_s_setprio(1);
      acc[a] = mfma16(kf0, qf0, acc[a]);
      acc[a] = mfma16(kf1, qf1, acc[a]);
      __builtin_amdgcn_s_setprio(0);
    }
    // score store (NT) + e = exp2(S*log2e + log2(prior+eps)) + P-tile (bf16)
#pragma unroll
    for (int n = 0; n < 8; ++n) {
      const int a = t * 8 + n;
      __builtin_nontemporal_store((float4v)acc[a],
                                  (float4v*)(sb + t * 128 + n * 16));
      f32x4 e;
#pragma unroll
      for (int r = 0; r < 4; ++r)
        e[r] = fast_exp2(acc[a][r] * 1.44269504f + fast_log2(pr[n][r] + 1e-8f));
      rsum += (e[0] + e[1]) + (e[2] + e[3]);
      acc[a] = e;
      uint2v u;
      u.x = pack_bf(e[0], e[1]);
      u.y = pack_bf(e[2], e[3]);
      *(uint2v*)(pw + ((c * 256 + n * 32 + g * 8) ^ ((c & 7) << 4))) = u;
    }
    // y += V^T x P (SWAPPED): lane gets y[q=c][d = nt*16 + g*4 + r]
#pragma unroll
    for (int s = 0; s < 4; ++s) {
      short8 pf =
          *(const short8*)(pw + ((c * 256 + s * 64 + g * 16) ^ ((c & 7) << 4)));
#pragma unroll
      for (int nt = 0; nt < 4; ++nt) {
        const int vrow = nt * 16 + c;
        short8 vf = *(const short8*)(
            vl[cur] + ((vrow * 256 + s * 64 + g * 16) ^ ((vrow & 7) << 4)));
        __builtin_amdgcn_s_setprio(1);
        yacc[nt] = mfma16(vf, pf, yacc[nt]);
        __builtin_amdgcn_s_setprio(0);
      }
    }
    __syncthreads();  // tile t consumed by all waves; tile t+1 staged
  }

  // row sum for q-row c: spread across lanes differing in bits 4,5
  rsum += __shfl_xor(rsum, 16);
  rsum += __shfl_xor(rsum, 32);
  const float rs = 1.f / rsum;

  // prob = e * rs (dwordx4, NT) — lane's own q-row is c: rs correct.
#pragma unroll
  for (int n = 0; n < 32; ++n) {
    float4v p;
#pragma unroll
    for (int r = 0; r < 4; ++r) p[r] = acc[n][r] * rs;
    __builtin_nontemporal_store(p, (float4v*)(pb + n * 16));
  }

  // y store: lane holds y[q=c][d=nt*16+g*4+r] -> 4 packed 8B stores, own rs.
  unsigned short* yb_ =
      yb + ((size_t)b * 2048 + q0 + w * 16 + c) * 512 + h * 64;
#pragma unroll
  for (int nt = 0; nt < 4; ++nt) {
    uint2v u;
    u.x = pack_bf(yacc[nt][0] * rs, yacc[nt][1] * rs);
    u.y = pack_bf(yacc[nt][2] * rs, yacc[nt][3] * rs);
    *(uint2v*)(yb_ + nt * 16 + g * 4) = u;
  }
}

// ---- launcher ------------------------------------------------------------

extern "C" void kernel_launch(void* const* d_in, const int* in_sizes, int n_in,
                              void* d_out, int out_size, void* d_ws, size_t ws_size,
                              hipStream_t stream) {
  (void)in_sizes; (void)n_in; (void)out_size;
  const float* query = (const float*)d_in[0];
  const float* memory = (const float*)d_in[2];
  const float* prior = (const float*)d_in[4];
  const float* Wq = (const float*)d_in[5];
  const float* Wkv = (const float*)d_in[6];
  const float* Wo = (const float*)d_in[7];

  float* out = (float*)d_out;
  float* prob = out + (size_t)8 * 2048 * 512;          // 8388608
  float* score = prob + (size_t)64 * 2048 * 512;       // +67108864

  char* ws = (char*)d_ws;
  size_t off = 0;
  unsigned short* WqT = (unsigned short*)(ws + off);  off += (size_t)512 * 512 * 2;
  unsigned short* WkvT = (unsigned short*)(ws + off); off += (size_t)1024 * 512 * 2;
  unsigned short* WoT = (unsigned short*)(ws + off);  off += (size_t)512 * 512 * 2;
  unsigned short* Qb = (unsigned short*)(ws + off);   off += (size_t)64 * 2048 * 64 * 2;
  unsigned short* Kb = (unsigned short*)(ws + off);   off += (size_t)64 * 512 * 64 * 2;
  unsigned short* VT = (unsigned short*)(ws + off);   off += (size_t)64 * 64 * 512 * 2;
  unsigned short* yb = (unsigned short*)(ws + off);   off += (size_t)8 * 2048 * 512 * 2;
  if (ws_size < off) return;  // fail loudly (output stays poisoned)

  (void)hipFuncSetAttribute((const void*)attn_kernel,
                            hipFuncAttributeMaxDynamicSharedMemorySize, 81920);

  transpose_cvt3<<<1024, 256, 0, stream>>>(Wq, Wkv, Wo, WqT, WkvT, WoT);
  gemm_kernel<0><<<512, 256, 0, stream>>>(query, WqT, Qb, nullptr);
  gemm_kernel<1><<<256, 256, 0, stream>>>(memory, WkvT, Kb, VT);
  attn_kernel<<<2048, 256, 81920, stream>>>(Qb, Kb, VT, prior, score, prob, yb);
  gemm_kernel<2><<<512, 256, 0, stream>>>(yb, WoT, out, nullptr);
}